// Round 4
// baseline (3009.977 us; speedup 1.0000x reference)
//
#include <hip/hip_runtime.h>
#include <math.h>

// Problem constants (fixed by the harness).
#define BB 4096
#define TT 2048
#define LL 100

constexpr int NB = 16;       // batch items per block (= MFMA M)
constexpr int WG = 448;      // 7 waves, ALL layer-1; wave 3 also carries layer-2

#define L2E 1.44269504088896340736f

// Split-plane A-frag layout: hi and lo bf16 planes in separate LDS arrays,
// each phase 4 kt x 64 rows x 4 dwords (bf16x8 fragment per (kt,row)).
// H granule = kt*64 + (row ^ (row>>3)); L granule additionally XOR 1.
// R4 fix: without the ^1, each even/odd col16 lane PAIR writes the same
// (granule,jh) bank in H vs L (different address) -> 2-way conflict per
// half-wave = the residual 2.9e7 SQ_LDS_BANK_CONFLICT of R2/R3. With ^1,
// H-write banks occupy bit2==r&1 and L the complement: fully disjoint.
// b128 reads stay conflict-free in both planes (XOR1 permutes within the
// 8-granule bank classes).
#define AH(kt, row) (((kt) * 64 + ((row) ^ ((row) >> 3))) * 4)
#define AL(kt, row) (((kt) * 64 + (((row) ^ ((row) >> 3)) ^ 1)) * 4)

typedef short bf16x8 __attribute__((ext_vector_type(8)));
typedef float f32x4 __attribute__((ext_vector_type(4)));

union AF { int4 v; bf16x8 f; unsigned int w[4]; };

__device__ __forceinline__ float frcp(float x) { return __builtin_amdgcn_rcpf(x); }
__device__ __forceinline__ float fexp2(float x) {
#if __has_builtin(__builtin_amdgcn_exp2f)
    return __builtin_amdgcn_exp2f(x);
#else
    return exp2f(x);
#endif
}
// log2e pre-folded into weights/biases (v_exp_f32 IS 2^x).
__device__ __forceinline__ float sig2(float xp) { return frcp(1.0f + fexp2(-xp)); }
__device__ __forceinline__ float th2(float xpp) { return 1.0f - 2.0f * frcp(1.0f + fexp2(xpp)); }
__device__ __forceinline__ float ftanh_n(float x) { return th2(2.0f * L2E * x); }

__device__ __forceinline__ unsigned int xor1_lane(unsigned int v) {
#if __has_builtin(__builtin_amdgcn_mov_dpp)
    // quad_perm [1,0,3,2] = lane^1 exchange, pure VALU (no LDS pipe traffic)
    return (unsigned int)__builtin_amdgcn_mov_dpp((int)v, 0xB1, 0xF, 0xF, false);
#else
    return (unsigned int)__shfl_xor((int)v, 1, 64);
#endif
}
__device__ __forceinline__ unsigned int cvt_pk_bf16(float lo, float hi) {
    unsigned int d;
    asm("v_cvt_pk_bf16_f32 %0, %1, %2" : "=v"(d) : "v"(lo), "v"(hi));
    return d;
}

// Layer-1: gates padded 100->112 unit-slots; wave w owns all 4 gates of one
// 16-slot group. Slot-group permutation {0,1,2,6,3,4,5} puts the PAD group
// (slots 96..111) on wave 3 (solo on SIMD3). Layer-2 rides in the pad:
// B-column col16==8 of wave 3 holds W_ih2[g]. Biases enter as the exact-fp32
// MFMA C-input (binit); x rides A-column k=100 (pad lanes uu=100/101 deposit
// x_{t+1}; B-row k=100 = W_ih1 hi+mid split). Pads with uu>=102 never write
// (slots stay 0 from init).
// R4: pass 3's last K-tile runs gate-at-a-time with each gate's sigmoid/tanh
// chain issued right after that gate's chain completes -> trans ops overlap
// the remaining MFMA drain instead of serializing after it.
// Frag layouts (HW-verified R4-R6): A[m=lane&15][k=32kt+8quad+j];
// B[k][n=lane&15]; D col=lane&15, row=quad*4+reg.
__global__ void __launch_bounds__(WG)
__attribute__((amdgpu_waves_per_eu(2, 2)))
lstm2_kernel(const float* __restrict__ input,   // [B,T]
             const float* __restrict__ W_ih1,   // [400,1]
             const float* __restrict__ W_hh1,   // [400,100]
             const float* __restrict__ b_ih1,   // [400]
             const float* __restrict__ b_hh1,   // [400]
             const float* __restrict__ W_ih2,   // [4,100]
             const float* __restrict__ W_hh2,   // [4,1]
             const float* __restrict__ b_ih2,   // [4]
             const float* __restrict__ b_hh2,   // [4]
             float* __restrict__ out)           // [B,T]
{
    __shared__ __align__(16) unsigned int afragH[2][1024];   // 8 KB hi-bf16 plane
    __shared__ __align__(16) unsigned int afragL[2][1024];   // 8 KB lo-bf16 plane

    const int tid = threadIdx.x;
    const int wave = tid >> 6;       // 0..6
    const int lane = tid & 63;
    const int col16 = lane & 15;
    const int quad = lane >> 4;
    const int bg0 = blockIdx.x * NB;

    // ---------------- init ----------------
    for (int i = tid; i < 2 * 1024; i += WG) {
        (&afragH[0][0])[i] = 0u;
        (&afragL[0][0])[i] = 0u;
    }

    // slot-group permutation: wave 3 -> group 6 (slots 96..111)
    const int sb = (wave == 3) ? 6 : ((wave < 3) ? wave : wave - 1);
    const int uu = 16 * sb + col16;          // unit-slot owned by this lane
    const bool uvalid = (uu < LL);           // pad slots produce h=0
    const bool l2lane = (wave == 3) && (col16 == 8);   // layer-2 carrier lanes
    const bool xlane = (wave == 3) && (col16 == 4);    // x-depositor lanes (uu==100)
    const bool wr_en = (uu <= 101);          // uu>=102 slots stay 0 forever

    // gate scales folding log2e (i,f,o: sigmoid; g: tanh needs 2x)
    const float gsc[4] = {L2E, L2E, 2.0f * L2E, L2E};

    // Persistent B-fragments: bf16 hi/mid splits of scaled weights.
    // Normal lanes: W_hh1 rows (+ W_ih1 at k==100); l2lane: W_ih2 rows.
    bf16x8 bhi[4][4], bmid[4][4];
#pragma unroll
    for (int g = 0; g < 4; ++g)
#pragma unroll
        for (int kt = 0; kt < 4; ++kt)
#pragma unroll
            for (int j = 0; j < 8; ++j) {
                const int k = 32 * kt + 8 * quad + j;
                float w = 0.0f;
                if (k < LL) {
                    if (l2lane)       w = W_ih2[g * LL + k] * gsc[g];
                    else if (uvalid)  w = W_hh1[(100 * g + uu) * LL + k] * gsc[g];
                } else if (k == 100) {
                    if (!l2lane && uvalid) w = W_ih1[100 * g + uu] * gsc[g];
                }
                const unsigned int hh = cvt_pk_bf16(w, 0.0f) & 0xffffu;
                bhi[g][kt][j] = (short)hh;
                const float wres = w - __uint_as_float(hh << 16);
                bmid[g][kt][j] = (short)(cvt_pk_bf16(wres, 0.0f) & 0xffffu);
            }

    // Exact fp32 biases as the MFMA C-input.
    f32x4 binit[4];
#pragma unroll
    for (int g = 0; g < 4; ++g) {
        float bv = 0.0f;
        if (l2lane)      bv = (b_ih2[g] + b_hh2[g]) * gsc[g];
        else if (uvalid) bv = (b_ih1[100 * g + uu] + b_hh1[100 * g + uu]) * gsc[g];
        binit[g] = (f32x4){bv, bv, bv, bv};
    }

    float c1[4] = {0.f, 0.f, 0.f, 0.f};

    const int kt_u = uu >> 5;
    const int lnb = ((uu >> 3) & 3) * 16;
    const int jh = (uu & 7) >> 1;
    const bool oddu = (uu & 1) != 0;

    // Layer-2 recurrent state (l2lane only; 4 items per lane, m = 4*quad+r)
    float wh2s[4], h2v[4] = {0.f, 0.f, 0.f, 0.f}, c2v[4] = {0.f, 0.f, 0.f, 0.f};
#pragma unroll
    for (int g = 0; g < 4; ++g)
        wh2s[g] = l2lane ? W_hh2[g] * gsc[g] : 0.0f;

    __syncthreads();

    // ---- prologue: deposit x_0 into the k=100 column of phase 0 ----
    if (wave == 3 && (col16 == 4 || col16 == 5)) {
#pragma unroll
        for (int r = 0; r < 4; ++r) {
            const int m = 4 * quad + r;
            const float h = (col16 == 4) ? input[(size_t)(bg0 + m) * TT] : 0.0f;
            const float hq = __uint_as_float(xor1_lane(__float_as_uint(h)));
            const unsigned int tpk = cvt_pk_bf16(h, hq);
            const float hl_own = h - __uint_as_float(tpk << 16);
            const float hl_par = hq - __uint_as_float(tpk & 0xffff0000u);
            const unsigned int lod = cvt_pk_bf16(hl_par, hl_own);
            if (oddu) afragL[0][AL(3, lnb + m) + jh] = lod;
            else      afragH[0][AH(3, lnb + m) + jh] = tpk;
        }
    }
    __syncthreads();

    // ---------------- time loop (one barrier per step) ----------------
    for (int t = 0; t <= TT; ++t) {
        const int p = t & 1, pn = p ^ 1;

        // wave 3 also runs at t==TT to produce the final layer-2 output
        if (t < TT || wave == 3) {
            // x_{t+1} prefetch (4 lanes of wave 3; L1-resident lines).
            float xnext[4] = {0.f, 0.f, 0.f, 0.f};
            if (xlane && t + 1 < TT) {
#pragma unroll
                for (int r = 0; r < 4; ++r)
                    xnext[r] = input[(size_t)(bg0 + 4 * quad + r) * TT + (t + 1)];
            }

            // ---- all A-frag reads hoisted: LDS pipe gets the full burst ----
            AF ahi[4], alo[4];
#pragma unroll
            for (int kt = 0; kt < 4; ++kt)
                ahi[kt].v = *(const int4*)&afragH[p][AH(kt, lane)];
#pragma unroll
            for (int kt = 0; kt < 4; ++kt)
                alo[kt].v = *(const int4*)&afragL[p][AL(kt, lane)];

            // pass 1: ahi * bhi, bias preloaded via C
            f32x4 acc[4];
#pragma unroll
            for (int g = 0; g < 4; ++g)
                acc[g] = __builtin_amdgcn_mfma_f32_16x16x32_bf16(ahi[0].f, bhi[g][0], binit[g], 0, 0, 0);
#pragma unroll
            for (int kt = 1; kt < 4; ++kt)
#pragma unroll
                for (int g = 0; g < 4; ++g)
                    acc[g] = __builtin_amdgcn_mfma_f32_16x16x32_bf16(ahi[kt].f, bhi[g][kt], acc[g], 0, 0, 0);
            // pass 2: ahi * bmid
#pragma unroll
            for (int kt = 0; kt < 4; ++kt)
#pragma unroll
                for (int g = 0; g < 4; ++g)
                    acc[g] = __builtin_amdgcn_mfma_f32_16x16x32_bf16(ahi[kt].f, bmid[g][kt], acc[g], 0, 0, 0);
            // pass 3, kt 0..2: alo * bhi (4 independent gate chains)
#pragma unroll
            for (int kt = 0; kt < 3; ++kt)
#pragma unroll
                for (int g = 0; g < 4; ++g)
                    acc[g] = __builtin_amdgcn_mfma_f32_16x16x32_bf16(alo[kt].f, bhi[g][kt], acc[g], 0, 0, 0);

            // ---- pass-3 kt3 gate-at-a-time, update chains issued early ----
            float iv[4], fv[4], ta[4];

            acc[0] = __builtin_amdgcn_mfma_f32_16x16x32_bf16(alo[3].f, bhi[0][3], acc[0], 0, 0, 0);
#pragma unroll
            for (int r = 0; r < 4; ++r) iv[r] = sig2(acc[0][r]);

            acc[1] = __builtin_amdgcn_mfma_f32_16x16x32_bf16(alo[3].f, bhi[1][3], acc[1], 0, 0, 0);
#pragma unroll
            for (int r = 0; r < 4; ++r) fv[r] = sig2(acc[1][r]);

            acc[2] = __builtin_amdgcn_mfma_f32_16x16x32_bf16(alo[3].f, bhi[2][3], acc[2], 0, 0, 0);
#pragma unroll
            for (int r = 0; r < 4; ++r) {
                const float gv = th2(acc[2][r]);
                const float c = fv[r] * c1[r] + iv[r] * gv;
                c1[r] = c;
                ta[r] = 2.0f * L2E * c;    // tanh argument, chain starts early
            }

            acc[3] = __builtin_amdgcn_mfma_f32_16x16x32_bf16(alo[3].f, bhi[3][3], acc[3], 0, 0, 0);

            // ---- layer 2 (l2lane): acc[g][r] = b2 + dot(W_ih2[g], h1_{t-1}[4q+r]) ----
            if (l2lane && t >= 1) {
#pragma unroll
                for (int r = 0; r < 4; ++r) {
                    const float p0 = fmaf(wh2s[0], h2v[r], acc[0][r]);
                    const float p1 = fmaf(wh2s[1], h2v[r], acc[1][r]);
                    const float p2 = fmaf(wh2s[2], h2v[r], acc[2][r]);
                    const float p3 = fmaf(wh2s[3], h2v[r], acc[3][r]);
                    const float i2 = sig2(p0), f2 = sig2(p1), g2 = th2(p2), o2 = sig2(p3);
                    c2v[r] = f2 * c2v[r] + i2 * g2;
                    h2v[r] = o2 * ftanh_n(c2v[r]);
                    out[(size_t)(bg0 + 4 * quad + r) * TT + (t - 1)] = h2v[r];
                }
            }

            // ---- o-gate, h, split-plane pack + write ----
            if (t < TT) {
#pragma unroll
                for (int r = 0; r < 4; ++r) {
                    const int m = 4 * quad + r;
                    const float ov = sig2(acc[3][r]);
                    const float th = th2(ta[r]);
                    const float h = uvalid ? (ov * th) : xnext[r];
                    // pair-pack via DPP + cvt_pk: even lane emits hi-plane dword
                    // (hh_e|hh_o), odd lane emits lo-plane dword (hl_e|hl_o).
                    // lo plane self-compensates cvt_pk's rounding of the hi.
                    const float hq = __uint_as_float(xor1_lane(__float_as_uint(h)));
                    const unsigned int tpk = cvt_pk_bf16(h, hq);
                    const float hl_own = h - __uint_as_float(tpk << 16);
                    const float hl_par = hq - __uint_as_float(tpk & 0xffff0000u);
                    const unsigned int lod = cvt_pk_bf16(hl_par, hl_own);
                    if (wr_en) {
                        if (oddu) afragL[pn][AL(kt_u, lnb + m) + jh] = lod;
                        else      afragH[pn][AH(kt_u, lnb + m) + jh] = tpk;
                    }
                }
            }
        }

        __syncthreads();   // h1_t (afragH/L[pn]) visible for step t+1
    }
}

extern "C" void kernel_launch(void* const* d_in, const int* in_sizes, int n_in,
                              void* d_out, int out_size, void* d_ws, size_t ws_size,
                              hipStream_t stream) {
    const float* input = (const float*)d_in[0];
    const float* W_ih1 = (const float*)d_in[1];
    const float* W_hh1 = (const float*)d_in[2];
    const float* b_ih1 = (const float*)d_in[3];
    const float* b_hh1 = (const float*)d_in[4];
    const float* W_ih2 = (const float*)d_in[5];
    const float* W_hh2 = (const float*)d_in[6];
    const float* b_ih2 = (const float*)d_in[7];
    const float* b_hh2 = (const float*)d_in[8];
    float* out = (float*)d_out;

    dim3 grid(BB / NB);   // 256 workgroups -> 1 per CU
    dim3 block(WG);       // 448 threads = 7 waves
    lstm2_kernel<<<grid, block, 0, stream>>>(input, W_ih1, W_hh1, b_ih1, b_hh1,
                                             W_ih2, W_hh2, b_ih2, b_hh2, out);
}

// Round 5
// 2923.654 us; speedup vs baseline: 1.0295x; 1.0295x over previous
//
#include <hip/hip_runtime.h>
#include <math.h>

// Problem constants (fixed by the harness).
#define BB 4096
#define TT 2048
#define LL 100

constexpr int NB = 16;       // batch items per block (= MFMA M)
constexpr int WG = 448;      // 7 waves, ALL layer-1; wave 3 also carries layer-2

#define L2E 1.44269504088896340736f

// Split-plane A-frag layout: hi and lo bf16 planes in separate LDS arrays,
// each phase 4 kt x 64 rows x 4 dwords (bf16x8 fragment per (kt,row)).
// H granule = kt*64 + (row ^ (row>>3)); L granule additionally XOR 1.
// Without the ^1, each even/odd col16 lane PAIR writes the same (granule,jh)
// bank in H vs L (different address) -> 2-way conflict per half-wave (the
// residual 2.9e7 of R2/R3). With ^1 the write banks are fully disjoint —
// counter-verified 0 in R4. b128 reads stay conflict-free in both planes.
// SCHEDULE NOTE (R4 lesson): keep alo reads DEFERRED behind pass 2 and the
// update phase BATCHED after all MFMAs — hand-interleaving trans ops with
// dependent MFMAs (R4) added ~300us of stall. Do not re-attempt.
#define AH(kt, row) (((kt) * 64 + ((row) ^ ((row) >> 3))) * 4)
#define AL(kt, row) (((kt) * 64 + (((row) ^ ((row) >> 3)) ^ 1)) * 4)

typedef short bf16x8 __attribute__((ext_vector_type(8)));
typedef float f32x4 __attribute__((ext_vector_type(4)));

union AF { int4 v; bf16x8 f; unsigned int w[4]; };

__device__ __forceinline__ float frcp(float x) { return __builtin_amdgcn_rcpf(x); }
__device__ __forceinline__ float fexp2(float x) {
#if __has_builtin(__builtin_amdgcn_exp2f)
    return __builtin_amdgcn_exp2f(x);
#else
    return exp2f(x);
#endif
}
// log2e pre-folded into weights/biases (v_exp_f32 IS 2^x).
__device__ __forceinline__ float sig2(float xp) { return frcp(1.0f + fexp2(-xp)); }
__device__ __forceinline__ float th2(float xpp) { return 1.0f - 2.0f * frcp(1.0f + fexp2(xpp)); }
__device__ __forceinline__ float ftanh_n(float x) { return th2(2.0f * L2E * x); }

__device__ __forceinline__ unsigned int xor1_lane(unsigned int v) {
#if __has_builtin(__builtin_amdgcn_mov_dpp)
    // quad_perm [1,0,3,2] = lane^1 exchange, pure VALU (no LDS pipe traffic)
    return (unsigned int)__builtin_amdgcn_mov_dpp((int)v, 0xB1, 0xF, 0xF, false);
#else
    return (unsigned int)__shfl_xor((int)v, 1, 64);
#endif
}
__device__ __forceinline__ unsigned int cvt_pk_bf16(float lo, float hi) {
    unsigned int d;
    asm("v_cvt_pk_bf16_f32 %0, %1, %2" : "=v"(d) : "v"(lo), "v"(hi));
    return d;
}

// Layer-1: gates padded 100->112 unit-slots; wave w owns all 4 gates of one
// 16-slot group. Slot-group permutation {0,1,2,6,3,4,5} puts the PAD group
// (slots 96..111) on wave 3 (solo on SIMD3). Layer-2 rides in the pad:
// B-column col16==8 of wave 3 holds W_ih2[g]. Biases enter as the exact-fp32
// MFMA C-input (binit); x rides A-column k=100 (pad lanes uu=100/101 deposit
// x_{t+1}; B-row k=100 = W_ih1 hi+mid split). Pads with uu>=102 never write
// (slots stay 0 from init).
// Frag layouts (HW-verified R4-R6): A[m=lane&15][k=32kt+8quad+j];
// B[k][n=lane&15]; D col=lane&15, row=quad*4+reg.
__global__ void __launch_bounds__(WG)
__attribute__((amdgpu_waves_per_eu(2, 2)))
lstm2_kernel(const float* __restrict__ input,   // [B,T]
             const float* __restrict__ W_ih1,   // [400,1]
             const float* __restrict__ W_hh1,   // [400,100]
             const float* __restrict__ b_ih1,   // [400]
             const float* __restrict__ b_hh1,   // [400]
             const float* __restrict__ W_ih2,   // [4,100]
             const float* __restrict__ W_hh2,   // [4,1]
             const float* __restrict__ b_ih2,   // [4]
             const float* __restrict__ b_hh2,   // [4]
             float* __restrict__ out)           // [B,T]
{
    __shared__ __align__(16) unsigned int afragH[2][1024];   // 8 KB hi-bf16 plane
    __shared__ __align__(16) unsigned int afragL[2][1024];   // 8 KB lo-bf16 plane

    const int tid = threadIdx.x;
    const int wave = tid >> 6;       // 0..6
    const int lane = tid & 63;
    const int col16 = lane & 15;
    const int quad = lane >> 4;
    const int bg0 = blockIdx.x * NB;

    // ---------------- init ----------------
    for (int i = tid; i < 2 * 1024; i += WG) {
        (&afragH[0][0])[i] = 0u;
        (&afragL[0][0])[i] = 0u;
    }

    // slot-group permutation: wave 3 -> group 6 (slots 96..111)
    const int sb = (wave == 3) ? 6 : ((wave < 3) ? wave : wave - 1);
    const int uu = 16 * sb + col16;          // unit-slot owned by this lane
    const bool uvalid = (uu < LL);           // pad slots produce h=0
    const bool l2lane = (wave == 3) && (col16 == 8);   // layer-2 carrier lanes
    const bool xlane = (wave == 3) && (col16 == 4);    // x-depositor lanes (uu==100)
    const bool wr_en = (uu <= 101);          // uu>=102 slots stay 0 forever

    // gate scales folding log2e (i,f,o: sigmoid; g: tanh needs 2x)
    const float gsc[4] = {L2E, L2E, 2.0f * L2E, L2E};

    // Persistent B-fragments: bf16 hi/mid splits of scaled weights.
    // Normal lanes: W_hh1 rows (+ W_ih1 at k==100); l2lane: W_ih2 rows.
    bf16x8 bhi[4][4], bmid[4][4];
#pragma unroll
    for (int g = 0; g < 4; ++g)
#pragma unroll
        for (int kt = 0; kt < 4; ++kt)
#pragma unroll
            for (int j = 0; j < 8; ++j) {
                const int k = 32 * kt + 8 * quad + j;
                float w = 0.0f;
                if (k < LL) {
                    if (l2lane)       w = W_ih2[g * LL + k] * gsc[g];
                    else if (uvalid)  w = W_hh1[(100 * g + uu) * LL + k] * gsc[g];
                } else if (k == 100) {
                    if (!l2lane && uvalid) w = W_ih1[100 * g + uu] * gsc[g];
                }
                const unsigned int hh = cvt_pk_bf16(w, 0.0f) & 0xffffu;
                bhi[g][kt][j] = (short)hh;
                const float wres = w - __uint_as_float(hh << 16);
                bmid[g][kt][j] = (short)(cvt_pk_bf16(wres, 0.0f) & 0xffffu);
            }

    // Exact fp32 biases as the MFMA C-input.
    f32x4 binit[4];
#pragma unroll
    for (int g = 0; g < 4; ++g) {
        float bv = 0.0f;
        if (l2lane)      bv = (b_ih2[g] + b_hh2[g]) * gsc[g];
        else if (uvalid) bv = (b_ih1[100 * g + uu] + b_hh1[100 * g + uu]) * gsc[g];
        binit[g] = (f32x4){bv, bv, bv, bv};
    }

    float c1[4] = {0.f, 0.f, 0.f, 0.f};

    const int kt_u = uu >> 5;
    const int lnb = ((uu >> 3) & 3) * 16;
    const int jh = (uu & 7) >> 1;
    const bool oddu = (uu & 1) != 0;

    // Layer-2 recurrent state (l2lane only; 4 items per lane, m = 4*quad+r)
    float wh2s[4], h2v[4] = {0.f, 0.f, 0.f, 0.f}, c2v[4] = {0.f, 0.f, 0.f, 0.f};
#pragma unroll
    for (int g = 0; g < 4; ++g)
        wh2s[g] = l2lane ? W_hh2[g] * gsc[g] : 0.0f;

    __syncthreads();

    // ---- prologue: deposit x_0 into the k=100 column of phase 0 ----
    if (wave == 3 && (col16 == 4 || col16 == 5)) {
#pragma unroll
        for (int r = 0; r < 4; ++r) {
            const int m = 4 * quad + r;
            const float h = (col16 == 4) ? input[(size_t)(bg0 + m) * TT] : 0.0f;
            const float hq = __uint_as_float(xor1_lane(__float_as_uint(h)));
            const unsigned int tpk = cvt_pk_bf16(h, hq);
            const float hl_own = h - __uint_as_float(tpk << 16);
            const float hl_par = hq - __uint_as_float(tpk & 0xffff0000u);
            const unsigned int lod = cvt_pk_bf16(hl_par, hl_own);
            if (oddu) afragL[0][AL(3, lnb + m) + jh] = lod;
            else      afragH[0][AH(3, lnb + m) + jh] = tpk;
        }
    }
    __syncthreads();

    // ---------------- time loop (one barrier per step) ----------------
    for (int t = 0; t <= TT; ++t) {
        const int p = t & 1, pn = p ^ 1;

        // wave 3 also runs at t==TT to produce the final layer-2 output
        if (t < TT || wave == 3) {
            // x_{t+1} prefetch (4 lanes of wave 3; L1-resident lines).
            float xnext[4] = {0.f, 0.f, 0.f, 0.f};
            if (xlane && t + 1 < TT) {
#pragma unroll
                for (int r = 0; r < 4; ++r)
                    xnext[r] = input[(size_t)(bg0 + 4 * quad + r) * TT + (t + 1)];
            }

            // ---- hi-plane A-frags (h1_{t-1} hi bf16): direct b128 -> MFMA ----
            AF ahi[4];
#pragma unroll
            for (int kt = 0; kt < 4; ++kt)
                ahi[kt].v = *(const int4*)&afragH[p][AH(kt, lane)];

            // pass 1: ahi * bhi, bias preloaded via C
            f32x4 acc[4];
#pragma unroll
            for (int g = 0; g < 4; ++g)
                acc[g] = __builtin_amdgcn_mfma_f32_16x16x32_bf16(ahi[0].f, bhi[g][0], binit[g], 0, 0, 0);
#pragma unroll
            for (int kt = 1; kt < 4; ++kt)
#pragma unroll
                for (int g = 0; g < 4; ++g)
                    acc[g] = __builtin_amdgcn_mfma_f32_16x16x32_bf16(ahi[kt].f, bhi[g][kt], acc[g], 0, 0, 0);
            // pass 2: ahi * bmid (only needs ahi -> covers the alo load latency)
#pragma unroll
            for (int kt = 0; kt < 4; ++kt)
#pragma unroll
                for (int g = 0; g < 4; ++g)
                    acc[g] = __builtin_amdgcn_mfma_f32_16x16x32_bf16(ahi[kt].f, bmid[g][kt], acc[g], 0, 0, 0);

            // ---- lo-plane A-frags, deferred (hidden under pass 2) ----
            AF alo[4];
#pragma unroll
            for (int kt = 0; kt < 4; ++kt)
                alo[kt].v = *(const int4*)&afragL[p][AL(kt, lane)];
            // pass 3: alo * bhi
#pragma unroll
            for (int kt = 0; kt < 4; ++kt)
#pragma unroll
                for (int g = 0; g < 4; ++g)
                    acc[g] = __builtin_amdgcn_mfma_f32_16x16x32_bf16(alo[kt].f, bhi[g][kt], acc[g], 0, 0, 0);

            // ---- layer 2 (l2lane): acc[g][r] = b2 + dot(W_ih2[g], h1_{t-1}[4q+r]) ----
            if (l2lane && t >= 1) {
#pragma unroll
                for (int r = 0; r < 4; ++r) {
                    const float p0 = fmaf(wh2s[0], h2v[r], acc[0][r]);
                    const float p1 = fmaf(wh2s[1], h2v[r], acc[1][r]);
                    const float p2 = fmaf(wh2s[2], h2v[r], acc[2][r]);
                    const float p3 = fmaf(wh2s[3], h2v[r], acc[3][r]);
                    const float i2 = sig2(p0), f2 = sig2(p1), g2 = th2(p2), o2 = sig2(p3);
                    c2v[r] = f2 * c2v[r] + i2 * g2;
                    h2v[r] = o2 * ftanh_n(c2v[r]);
                    out[(size_t)(bg0 + 4 * quad + r) * TT + (t - 1)] = h2v[r];
                }
            }

            // ---- layer-1 cell update + split-plane h write-back ----
            if (t < TT) {
#pragma unroll
                for (int r = 0; r < 4; ++r) {
                    const int m = 4 * quad + r;
                    // bias and x already inside acc -> gates are acc directly
                    const float iv = sig2(acc[0][r]);
                    const float fv = sig2(acc[1][r]);
                    const float gv = th2(acc[2][r]);
                    const float ov = sig2(acc[3][r]);
                    const float c = fv * c1[r] + iv * gv;
                    c1[r] = c;
                    // valid units: h; pad lanes: 0 except uu==100 carries x_{t+1}
                    const float h = uvalid ? (ov * ftanh_n(c)) : xnext[r];
                    // pair-pack via DPP + cvt_pk: even lane emits hi-plane dword
                    // (hh_e|hh_o), odd lane emits lo-plane dword (hl_e|hl_o).
                    // lo plane self-compensates cvt_pk's rounding of the hi.
                    const float hq = __uint_as_float(xor1_lane(__float_as_uint(h)));
                    const unsigned int tpk = cvt_pk_bf16(h, hq);
                    const float hl_own = h - __uint_as_float(tpk << 16);
                    const float hl_par = hq - __uint_as_float(tpk & 0xffff0000u);
                    const unsigned int lod = cvt_pk_bf16(hl_par, hl_own);
                    if (wr_en) {
                        if (oddu) afragL[pn][AL(kt_u, lnb + m) + jh] = lod;
                        else      afragH[pn][AH(kt_u, lnb + m) + jh] = tpk;
                    }
                }
            }
        }

        __syncthreads();   // h1_t (afragH/L[pn]) visible for step t+1
    }
}

extern "C" void kernel_launch(void* const* d_in, const int* in_sizes, int n_in,
                              void* d_out, int out_size, void* d_ws, size_t ws_size,
                              hipStream_t stream) {
    const float* input = (const float*)d_in[0];
    const float* W_ih1 = (const float*)d_in[1];
    const float* W_hh1 = (const float*)d_in[2];
    const float* b_ih1 = (const float*)d_in[3];
    const float* b_hh1 = (const float*)d_in[4];
    const float* W_ih2 = (const float*)d_in[5];
    const float* W_hh2 = (const float*)d_in[6];
    const float* b_ih2 = (const float*)d_in[7];
    const float* b_hh2 = (const float*)d_in[8];
    float* out = (float*)d_out;

    dim3 grid(BB / NB);   // 256 workgroups -> 1 per CU
    dim3 block(WG);       // 448 threads = 7 waves
    lstm2_kernel<<<grid, block, 0, stream>>>(input, W_ih1, W_hh1, b_ih1, b_hh1,
                                             W_ih2, W_hh2, b_ih2, b_hh2, out);
}

// Round 6
// 2782.873 us; speedup vs baseline: 1.0816x; 1.0506x over previous
//
#include <hip/hip_runtime.h>
#include <math.h>

// Problem constants (fixed by the harness).
#define BB 4096
#define TT 2048
#define LL 100

constexpr int NB = 16;       // batch items per block (= MFMA M)
constexpr int WG = 448;      // 7 waves, ALL layer-1; wave 3 also carries layer-2

#define L2E 1.44269504088896340736f

// Split-plane A-frag layout: hi and lo bf16 planes in separate LDS arrays,
// each phase 4 kt x 64 rows x 4 dwords (bf16x8 fragment per (kt,row)).
// Granule (16B) index = kt*64 + (row ^ (row>>3)).  SAME layout for H and L
// (R3's proven-fast read path: alo address = ahi address + const offset).
// R6: h write-back is per-lane ds_write_b16 into each plane (own halfword)
// instead of DPP-paired b32 dwords.  Write conflict enumeration: per b16
// write instr, each 8-lane octet hits 4 dwords of ONE granule (2 lanes per
// dword = same-dword, free) and the 8 rows' granules are distinct mod 8
// (rows r,4+r,...,28+r -> g mod 8 = {0,4,1,5,2,6,3,7}) -> all 32 banks,
// conflict-free by construction.  H and L writes are separate instructions,
// so R3's residual H-vs-L paired-lane collision (2.9e7) is gone too.
// SCHEDULE NOTE (R4 lesson): keep alo reads DEFERRED behind pass 2 and the
// update phase BATCHED after all MFMAs — hand-interleaving trans ops with
// dependent MFMAs added ~300us of stall. Do not re-attempt.
#define AH(kt, row) (((kt) * 64 + ((row) ^ ((row) >> 3))) * 4)

typedef short bf16x8 __attribute__((ext_vector_type(8)));
typedef float f32x4 __attribute__((ext_vector_type(4)));

union AF { int4 v; bf16x8 f; unsigned int w[4]; };

__device__ __forceinline__ float frcp(float x) { return __builtin_amdgcn_rcpf(x); }
__device__ __forceinline__ float fexp2(float x) {
#if __has_builtin(__builtin_amdgcn_exp2f)
    return __builtin_amdgcn_exp2f(x);
#else
    return exp2f(x);
#endif
}
// log2e pre-folded into weights/biases (v_exp_f32 IS 2^x).
__device__ __forceinline__ float sig2(float xp) { return frcp(1.0f + fexp2(-xp)); }
__device__ __forceinline__ float th2(float xpp) { return 1.0f - 2.0f * frcp(1.0f + fexp2(xpp)); }
__device__ __forceinline__ float ftanh_n(float x) { return th2(2.0f * L2E * x); }

__device__ __forceinline__ unsigned int cvt_pk_bf16(float lo, float hi) {
    unsigned int d;
    asm("v_cvt_pk_bf16_f32 %0, %1, %2" : "=v"(d) : "v"(lo), "v"(hi));
    return d;
}

// Layer-1: gates padded 100->112 unit-slots; wave w owns all 4 gates of one
// 16-slot group. Slot-group permutation {0,1,2,6,3,4,5} puts the PAD group
// (slots 96..111) on wave 3 (solo on SIMD3). Layer-2 rides in the pad:
// B-column col16==8 of wave 3 holds W_ih2[g]. Biases enter as the exact-fp32
// MFMA C-input (binit); x rides A-column k=100 (lane uu==100 deposits
// x_{t+1} each step; B-row k=100 = W_ih1 hi+mid split). Slots 101..111 are
// written once (zero-init) and never touched again.
// Frag layouts (HW-verified R4-R6): A[m=lane&15][k=32kt+8quad+j];
// B[k][n=lane&15]; D col=lane&15, row=quad*4+reg.
__global__ void __launch_bounds__(WG)
__attribute__((amdgpu_waves_per_eu(2, 2)))
lstm2_kernel(const float* __restrict__ input,   // [B,T]
             const float* __restrict__ W_ih1,   // [400,1]
             const float* __restrict__ W_hh1,   // [400,100]
             const float* __restrict__ b_ih1,   // [400]
             const float* __restrict__ b_hh1,   // [400]
             const float* __restrict__ W_ih2,   // [4,100]
             const float* __restrict__ W_hh2,   // [4,1]
             const float* __restrict__ b_ih2,   // [4]
             const float* __restrict__ b_hh2,   // [4]
             float* __restrict__ out)           // [B,T]
{
    __shared__ __align__(16) unsigned int afragH[2][1024];   // 8 KB hi-bf16 plane
    __shared__ __align__(16) unsigned int afragL[2][1024];   // 8 KB lo-bf16 plane

    const int tid = threadIdx.x;
    const int wave = tid >> 6;       // 0..6
    const int lane = tid & 63;
    const int col16 = lane & 15;
    const int quad = lane >> 4;
    const int bg0 = blockIdx.x * NB;

    // ---------------- init ----------------
    for (int i = tid; i < 2 * 1024; i += WG) {
        (&afragH[0][0])[i] = 0u;
        (&afragL[0][0])[i] = 0u;
    }

    // slot-group permutation: wave 3 -> group 6 (slots 96..111)
    const int sb = (wave == 3) ? 6 : ((wave < 3) ? wave : wave - 1);
    const int uu = 16 * sb + col16;          // unit-slot owned by this lane
    const bool uvalid = (uu < LL);           // pad slots produce h=0
    const bool l2lane = (wave == 3) && (col16 == 8);   // layer-2 carrier lanes
    const bool xlane = (wave == 3) && (col16 == 4);    // x-depositor lanes (uu==100)
    const bool wr_en = (uu <= 100);          // uu>=101 slots stay 0 forever

    // gate scales folding log2e (i,f,o: sigmoid; g: tanh needs 2x)
    const float gsc[4] = {L2E, L2E, 2.0f * L2E, L2E};

    // Persistent B-fragments: bf16 hi/mid splits of scaled weights.
    // Normal lanes: W_hh1 rows (+ W_ih1 at k==100); l2lane: W_ih2 rows.
    bf16x8 bhi[4][4], bmid[4][4];
#pragma unroll
    for (int g = 0; g < 4; ++g)
#pragma unroll
        for (int kt = 0; kt < 4; ++kt)
#pragma unroll
            for (int j = 0; j < 8; ++j) {
                const int k = 32 * kt + 8 * quad + j;
                float w = 0.0f;
                if (k < LL) {
                    if (l2lane)       w = W_ih2[g * LL + k] * gsc[g];
                    else if (uvalid)  w = W_hh1[(100 * g + uu) * LL + k] * gsc[g];
                } else if (k == 100) {
                    if (!l2lane && uvalid) w = W_ih1[100 * g + uu] * gsc[g];
                }
                const unsigned int hh = cvt_pk_bf16(w, 0.0f) & 0xffffu;
                bhi[g][kt][j] = (short)hh;
                const float wres = w - __uint_as_float(hh << 16);
                bmid[g][kt][j] = (short)(cvt_pk_bf16(wres, 0.0f) & 0xffffu);
            }

    // Exact fp32 biases as the MFMA C-input.
    f32x4 binit[4];
#pragma unroll
    for (int g = 0; g < 4; ++g) {
        float bv = 0.0f;
        if (l2lane)      bv = (b_ih2[g] + b_hh2[g]) * gsc[g];
        else if (uvalid) bv = (b_ih1[100 * g + uu] + b_hh1[100 * g + uu]) * gsc[g];
        binit[g] = (f32x4){bv, bv, bv, bv};
    }

    float c1[4] = {0.f, 0.f, 0.f, 0.f};

    const int kt_u = uu >> 5;
    const int lnb = ((uu >> 3) & 3) * 16;
    const int jh = (uu & 7) >> 1;
    const int hwo = uu & 1;                  // halfword parity within the dword

    // Layer-2 recurrent state (l2lane only; 4 items per lane, m = 4*quad+r)
    float wh2s[4], h2v[4] = {0.f, 0.f, 0.f, 0.f}, c2v[4] = {0.f, 0.f, 0.f, 0.f};
#pragma unroll
    for (int g = 0; g < 4; ++g)
        wh2s[g] = l2lane ? W_hh2[g] * gsc[g] : 0.0f;

    __syncthreads();

    // ---- prologue: deposit x_0 into the k=100 column of phase 0 ----
    if (xlane) {
#pragma unroll
        for (int r = 0; r < 4; ++r) {
            const int m = 4 * quad + r;
            const float x0 = input[(size_t)(bg0 + m) * TT];
            const unsigned int hh = cvt_pk_bf16(x0, x0);
            const float hl = x0 - __uint_as_float(hh << 16);
            const unsigned int hlp = cvt_pk_bf16(hl, hl);
            const int hw = (AH(3, lnb + m) + jh) * 2 + hwo;
            ((short*)&afragH[0][0])[hw] = (short)hh;
            ((short*)&afragL[0][0])[hw] = (short)hlp;
        }
    }
    __syncthreads();

    // ---------------- time loop (one barrier per step) ----------------
    for (int t = 0; t <= TT; ++t) {
        const int p = t & 1, pn = p ^ 1;

        // wave 3 also runs at t==TT to produce the final layer-2 output
        if (t < TT || wave == 3) {
            // x_{t+1} prefetch (4 lanes of wave 3; L2-resident lines).
            float xnext[4] = {0.f, 0.f, 0.f, 0.f};
            if (xlane && t + 1 < TT) {
#pragma unroll
                for (int r = 0; r < 4; ++r)
                    xnext[r] = input[(size_t)(bg0 + 4 * quad + r) * TT + (t + 1)];
            }

            // ---- hi-plane A-frags (h1_{t-1} hi bf16): direct b128 -> MFMA ----
            AF ahi[4];
#pragma unroll
            for (int kt = 0; kt < 4; ++kt)
                ahi[kt].v = *(const int4*)&afragH[p][AH(kt, lane)];

            // pass 1: ahi * bhi, bias preloaded via C
            f32x4 acc[4];
#pragma unroll
            for (int g = 0; g < 4; ++g)
                acc[g] = __builtin_amdgcn_mfma_f32_16x16x32_bf16(ahi[0].f, bhi[g][0], binit[g], 0, 0, 0);
#pragma unroll
            for (int kt = 1; kt < 4; ++kt)
#pragma unroll
                for (int g = 0; g < 4; ++g)
                    acc[g] = __builtin_amdgcn_mfma_f32_16x16x32_bf16(ahi[kt].f, bhi[g][kt], acc[g], 0, 0, 0);
            // pass 2: ahi * bmid (only needs ahi -> covers the alo load latency)
#pragma unroll
            for (int kt = 0; kt < 4; ++kt)
#pragma unroll
                for (int g = 0; g < 4; ++g)
                    acc[g] = __builtin_amdgcn_mfma_f32_16x16x32_bf16(ahi[kt].f, bmid[g][kt], acc[g], 0, 0, 0);

            // ---- lo-plane A-frags, deferred (hidden under pass 2) ----
            AF alo[4];
#pragma unroll
            for (int kt = 0; kt < 4; ++kt)
                alo[kt].v = *(const int4*)&afragL[p][AH(kt, lane)];
            // pass 3: alo * bhi
#pragma unroll
            for (int kt = 0; kt < 4; ++kt)
#pragma unroll
                for (int g = 0; g < 4; ++g)
                    acc[g] = __builtin_amdgcn_mfma_f32_16x16x32_bf16(alo[kt].f, bhi[g][kt], acc[g], 0, 0, 0);

            // ---- layer 2 (l2lane): acc[g][r] = b2 + dot(W_ih2[g], h1_{t-1}[4q+r]) ----
            if (l2lane && t >= 1) {
#pragma unroll
                for (int r = 0; r < 4; ++r) {
                    const float p0 = fmaf(wh2s[0], h2v[r], acc[0][r]);
                    const float p1 = fmaf(wh2s[1], h2v[r], acc[1][r]);
                    const float p2 = fmaf(wh2s[2], h2v[r], acc[2][r]);
                    const float p3 = fmaf(wh2s[3], h2v[r], acc[3][r]);
                    const float i2 = sig2(p0), f2 = sig2(p1), g2 = th2(p2), o2 = sig2(p3);
                    c2v[r] = f2 * c2v[r] + i2 * g2;
                    h2v[r] = o2 * ftanh_n(c2v[r]);
                    out[(size_t)(bg0 + 4 * quad + r) * TT + (t - 1)] = h2v[r];
                }
            }

            // ---- layer-1 cell update + per-lane b16 dual-plane write-back ----
            if (t < TT) {
#pragma unroll
                for (int r = 0; r < 4; ++r) {
                    const int m = 4 * quad + r;
                    // bias and x already inside acc -> gates are acc directly
                    const float iv = sig2(acc[0][r]);
                    const float fv = sig2(acc[1][r]);
                    const float gv = th2(acc[2][r]);
                    const float ov = sig2(acc[3][r]);
                    const float c = fv * c1[r] + iv * gv;
                    c1[r] = c;
                    // valid units: h; lane uu==100 carries x_{t+1}
                    const float h = uvalid ? (ov * ftanh_n(c)) : xnext[r];
                    if (wr_en) {
                        const unsigned int hh = cvt_pk_bf16(h, h);       // low16 = bf16rn(h)
                        const float hl = h - __uint_as_float(hh << 16);
                        const unsigned int hlp = cvt_pk_bf16(hl, hl);
                        const int hw = (AH(kt_u, lnb + m) + jh) * 2 + hwo;
                        ((short*)&afragH[pn][0])[hw] = (short)hh;
                        ((short*)&afragL[pn][0])[hw] = (short)hlp;
                    }
                }
            }
        }

        __syncthreads();   // h1_t (afragH/L[pn]) visible for step t+1
    }
}

extern "C" void kernel_launch(void* const* d_in, const int* in_sizes, int n_in,
                              void* d_out, int out_size, void* d_ws, size_t ws_size,
                              hipStream_t stream) {
    const float* input = (const float*)d_in[0];
    const float* W_ih1 = (const float*)d_in[1];
    const float* W_hh1 = (const float*)d_in[2];
    const float* b_ih1 = (const float*)d_in[3];
    const float* b_hh1 = (const float*)d_in[4];
    const float* W_ih2 = (const float*)d_in[5];
    const float* W_hh2 = (const float*)d_in[6];
    const float* b_ih2 = (const float*)d_in[7];
    const float* b_hh2 = (const float*)d_in[8];
    float* out = (float*)d_out;

    dim3 grid(BB / NB);   // 256 workgroups -> 1 per CU
    dim3 block(WG);       // 448 threads = 7 waves
    lstm2_kernel<<<grid, block, 0, stream>>>(input, W_ih1, W_hh1, b_ih1, b_hh1,
                                             W_ih2, W_hh2, b_ih2, b_hh2, out);
}

// Round 7
// 2322.396 us; speedup vs baseline: 1.2961x; 1.1983x over previous
//
#include <hip/hip_runtime.h>
#include <math.h>

// Problem constants (fixed by the harness).
#define BB 4096
#define TT 2048
#define LL 100

constexpr int NB = 16;       // batch items per block (= MFMA M)
constexpr int WG = 448;      // 7 waves, ALL layer-1; wave 3 also carries layer-2
constexpr int KT = 7;        // K-tiles of 32 ext-slots (224 = 2*112)

#define L2E 1.44269504088896340736f

// R7: interleaved-K fused multiply. A_ext[2i]=bf16hi(h_i), A_ext[2i+1]=
// bf16lo(h_i); B_ext[2i]=bf16hi(w_i), B_ext[2i+1]=bf16mid(w_i). ONE pass of
// K_eff=224 computes (ahi+alo)·(bhi+bmid) = h·w + O(2^-18) — strictly MORE
// accurate than the old 3-pass (which omitted alo·bmid), at 7 MFMA/gate
// instead of 12. 28 MFMA/wave vs 48.
// LDS: single plane, granule (16B) = kt*64 + (row ^ (row>>3)), row = reader
// lane for b128 reads (conflict-free as R2-R6). h write-back: k=2u,2u+1 are
// the two halfwords of dword (u&3) in granule (u>>4, m + 16*((u>>2)&3)) ->
// ONE ds_write_b32 per item; bank enumeration over a wave: exactly 2-way
// (free, m136). Each wave writes only kt==sb.
// SCHEDULE NOTE (R4 lesson): keep the update phase BATCHED after all MFMAs —
// hand-interleaving trans ops with dependent MFMAs added ~300us of stall.
#define AG(kt, row) (((kt) * 64 + ((row) ^ ((row) >> 3))) * 4)

typedef short bf16x8 __attribute__((ext_vector_type(8)));
typedef float f32x4 __attribute__((ext_vector_type(4)));

union AF { int4 v; bf16x8 f; unsigned int w[4]; };

__device__ __forceinline__ float frcp(float x) { return __builtin_amdgcn_rcpf(x); }
__device__ __forceinline__ float fexp2(float x) {
#if __has_builtin(__builtin_amdgcn_exp2f)
    return __builtin_amdgcn_exp2f(x);
#else
    return exp2f(x);
#endif
}
// log2e pre-folded into weights/biases (v_exp_f32 IS 2^x).
__device__ __forceinline__ float sig2(float xp) { return frcp(1.0f + fexp2(-xp)); }
__device__ __forceinline__ float th2(float xpp) { return 1.0f - 2.0f * frcp(1.0f + fexp2(xpp)); }
__device__ __forceinline__ float ftanh_n(float x) { return th2(2.0f * L2E * x); }

__device__ __forceinline__ unsigned int cvt_pk_bf16(float lo, float hi) {
    unsigned int d;
    asm("v_cvt_pk_bf16_f32 %0, %1, %2" : "=v"(d) : "v"(lo), "v"(hi));
    return d;
}

// Layer-1: gates padded 100->112 unit-slots; wave w owns all 4 gates of one
// 16-slot group. Slot-group permutation {0,1,2,6,3,4,5} puts the PAD group
// (slots 96..111) on wave 3 (solo on SIMD3). Layer-2 rides in the pad:
// B-column col16==8 of wave 3 holds W_ih2[g] (hi/mid split, same interleave).
// Biases enter as the exact-fp32 MFMA C-input (binit); x rides input-slot
// i=100 (ext-slots 200/201; lane uu==100 deposits x_{t+1} each step; B rows
// 200/201 = W_ih1 hi/mid). Slots i=101..111 stay zero from init.
// Frag layouts (HW-verified): A[m=lane&15][k=32kt+8quad+j];
// B[k][n=lane&15]; D col=lane&15, row=quad*4+reg.
__global__ void __launch_bounds__(WG)
__attribute__((amdgpu_waves_per_eu(2, 2)))
lstm2_kernel(const float* __restrict__ input,   // [B,T]
             const float* __restrict__ W_ih1,   // [400,1]
             const float* __restrict__ W_hh1,   // [400,100]
             const float* __restrict__ b_ih1,   // [400]
             const float* __restrict__ b_hh1,   // [400]
             const float* __restrict__ W_ih2,   // [4,100]
             const float* __restrict__ W_hh2,   // [4,1]
             const float* __restrict__ b_ih2,   // [4]
             const float* __restrict__ b_hh2,   // [4]
             float* __restrict__ out)           // [B,T]
{
    __shared__ __align__(16) unsigned int afrag[2][KT * 256];   // 14 KB interleaved hi/lo

    const int tid = threadIdx.x;
    const int wave = tid >> 6;       // 0..6
    const int lane = tid & 63;
    const int col16 = lane & 15;
    const int quad = lane >> 4;
    const int bg0 = blockIdx.x * NB;

    // ---------------- init ----------------
    for (int i = tid; i < 2 * KT * 256; i += WG) (&afrag[0][0])[i] = 0u;

    // slot-group permutation: wave 3 -> group 6 (slots 96..111)
    const int sb = (wave == 3) ? 6 : ((wave < 3) ? wave : wave - 1);
    const int uu = 16 * sb + col16;          // unit-slot owned by this lane
    const bool uvalid = (uu < LL);           // pad slots produce h=0
    const bool l2lane = (wave == 3) && (col16 == 8);   // layer-2 carrier lanes
    const bool xlane = (wave == 3) && (col16 == 4);    // x-depositor lanes (uu==100)
    const bool wr_en = (uu <= 100);          // uu>=101 slots stay 0 forever

    // gate scales folding log2e (i,f,o: sigmoid; g: tanh needs 2x)
    const float gsc[4] = {L2E, L2E, 2.0f * L2E, L2E};

    // Persistent B-fragments, interleaved (hi,mid) along K.
    // Normal lanes: W_hh1 rows (+ W_ih1 at i==100); l2lane: W_ih2 rows.
    bf16x8 bb[4][KT];
#pragma unroll
    for (int g = 0; g < 4; ++g)
#pragma unroll
        for (int kt = 0; kt < KT; ++kt)
#pragma unroll
            for (int j = 0; j < 8; ++j) {
                const int k = 32 * kt + 8 * quad + j;   // ext slot
                const int i = k >> 1;                   // input unit
                float w = 0.0f;
                if (i < LL) {
                    if (l2lane)       w = W_ih2[g * LL + i] * gsc[g];
                    else if (uvalid)  w = W_hh1[(100 * g + uu) * LL + i] * gsc[g];
                } else if (i == 100) {
                    if (!l2lane && uvalid) w = W_ih1[100 * g + uu] * gsc[g];
                }
                const unsigned int hh = cvt_pk_bf16(w, 0.0f) & 0xffffu;
                if (!(k & 1)) {
                    bb[g][kt][j] = (short)hh;
                } else {
                    const float wres = w - __uint_as_float(hh << 16);
                    bb[g][kt][j] = (short)(cvt_pk_bf16(wres, 0.0f) & 0xffffu);
                }
            }

    // Exact fp32 biases as the MFMA C-input.
    f32x4 binit[4];
#pragma unroll
    for (int g = 0; g < 4; ++g) {
        float bv = 0.0f;
        if (l2lane)      bv = (b_ih2[g] + b_hh2[g]) * gsc[g];
        else if (uvalid) bv = (b_ih1[100 * g + uu] + b_hh1[100 * g + uu]) * gsc[g];
        binit[g] = (f32x4){bv, bv, bv, bv};
    }

    float c1[4] = {0.f, 0.f, 0.f, 0.f};

    // write offsets: unit u's (hi,lo) pair = both halfwords of dword (u&3)
    // in granule (sb, m + 16*((col16>>2)&3)); one b32 per item r.
    int wofs[4];
#pragma unroll
    for (int r = 0; r < 4; ++r) {
        const int row = 4 * quad + r + 16 * ((col16 >> 2) & 3);
        wofs[r] = AG(sb, row) + (col16 & 3);
    }

    // Layer-2 recurrent state (l2lane only; 4 items per lane, m = 4*quad+r)
    float wh2s[4], h2v[4] = {0.f, 0.f, 0.f, 0.f}, c2v[4] = {0.f, 0.f, 0.f, 0.f};
#pragma unroll
    for (int g = 0; g < 4; ++g)
        wh2s[g] = l2lane ? W_hh2[g] * gsc[g] : 0.0f;

    __syncthreads();

    // ---- prologue: deposit x_0 (hi|lo packed dword) into phase 0 ----
    if (xlane) {
#pragma unroll
        for (int r = 0; r < 4; ++r) {
            const int m = 4 * quad + r;
            const float x0 = input[(size_t)(bg0 + m) * TT];
            const unsigned int hh = cvt_pk_bf16(x0, x0);
            const float hf = __uint_as_float(hh << 16);
            afrag[0][wofs[r]] = cvt_pk_bf16(x0, x0 - hf);
        }
    }
    __syncthreads();

    // ---------------- time loop (one barrier per step) ----------------
    for (int t = 0; t <= TT; ++t) {
        const int p = t & 1, pn = p ^ 1;

        // wave 3 also runs at t==TT to produce the final layer-2 output
        if (t < TT || wave == 3) {
            // x_{t+1} prefetch (4 lanes of wave 3; L2-resident lines).
            float xnext[4] = {0.f, 0.f, 0.f, 0.f};
            if (xlane && t + 1 < TT) {
#pragma unroll
                for (int r = 0; r < 4; ++r)
                    xnext[r] = input[(size_t)(bg0 + 4 * quad + r) * TT + (t + 1)];
            }

            // ---- A-frags (interleaved hi/lo of h1_{t-1}): b128 -> MFMA ----
            AF a[KT];
#pragma unroll
            for (int kt = 0; kt < KT; ++kt)
                a[kt].v = *(const int4*)&afrag[p][AG(kt, lane)];

            // single fused pass: 7 kt x 4 gates, bias preloaded via C
            f32x4 acc[4];
#pragma unroll
            for (int g = 0; g < 4; ++g)
                acc[g] = __builtin_amdgcn_mfma_f32_16x16x32_bf16(a[0].f, bb[g][0], binit[g], 0, 0, 0);
#pragma unroll
            for (int kt = 1; kt < KT; ++kt)
#pragma unroll
                for (int g = 0; g < 4; ++g)
                    acc[g] = __builtin_amdgcn_mfma_f32_16x16x32_bf16(a[kt].f, bb[g][kt], acc[g], 0, 0, 0);

            // ---- layer 2 (l2lane): acc[g][r] = b2 + dot(W_ih2[g], h1_{t-1}[4q+r]) ----
            if (l2lane && t >= 1) {
#pragma unroll
                for (int r = 0; r < 4; ++r) {
                    const float p0 = fmaf(wh2s[0], h2v[r], acc[0][r]);
                    const float p1 = fmaf(wh2s[1], h2v[r], acc[1][r]);
                    const float p2 = fmaf(wh2s[2], h2v[r], acc[2][r]);
                    const float p3 = fmaf(wh2s[3], h2v[r], acc[3][r]);
                    const float i2 = sig2(p0), f2 = sig2(p1), g2 = th2(p2), o2 = sig2(p3);
                    c2v[r] = f2 * c2v[r] + i2 * g2;
                    h2v[r] = o2 * ftanh_n(c2v[r]);
                    out[(size_t)(bg0 + 4 * quad + r) * TT + (t - 1)] = h2v[r];
                }
            }

            // ---- layer-1 cell update + single-dword (hi|lo) write-back ----
            if (t < TT) {
#pragma unroll
                for (int r = 0; r < 4; ++r) {
                    // bias and x already inside acc -> gates are acc directly
                    const float iv = sig2(acc[0][r]);
                    const float fv = sig2(acc[1][r]);
                    const float gv = th2(acc[2][r]);
                    const float ov = sig2(acc[3][r]);
                    const float c = fv * c1[r] + iv * gv;
                    c1[r] = c;
                    // valid units: h; lane uu==100 carries x_{t+1}
                    const float h = uvalid ? (ov * ftanh_n(c)) : xnext[r];
                    if (wr_en) {
                        const unsigned int hh = cvt_pk_bf16(h, h);   // low16 = bf16rn(h)
                        const float hf = __uint_as_float(hh << 16);
                        afrag[pn][wofs[r]] = cvt_pk_bf16(h, h - hf); // hi | lo<<16
                    }
                }
            }
        }

        __syncthreads();   // h1_t (afrag[pn]) visible for step t+1
    }
}

extern "C" void kernel_launch(void* const* d_in, const int* in_sizes, int n_in,
                              void* d_out, int out_size, void* d_ws, size_t ws_size,
                              hipStream_t stream) {
    const float* input = (const float*)d_in[0];
    const float* W_ih1 = (const float*)d_in[1];
    const float* W_hh1 = (const float*)d_in[2];
    const float* b_ih1 = (const float*)d_in[3];
    const float* b_hh1 = (const float*)d_in[4];
    const float* W_ih2 = (const float*)d_in[5];
    const float* W_hh2 = (const float*)d_in[6];
    const float* b_ih2 = (const float*)d_in[7];
    const float* b_hh2 = (const float*)d_in[8];
    float* out = (float*)d_out;

    dim3 grid(BB / NB);   // 256 workgroups -> 1 per CU
    dim3 block(WG);       // 448 threads = 7 waves
    lstm2_kernel<<<grid, block, 0, stream>>>(input, W_ih1, W_hh1, b_ih1, b_hh1,
                                             W_ih2, W_hh2, b_ih2, b_hh2, out);
}

// Round 8
// 2294.794 us; speedup vs baseline: 1.3117x; 1.0120x over previous
//
#include <hip/hip_runtime.h>
#include <math.h>

// Problem constants (fixed by the harness).
#define BB 4096
#define TT 2048
#define LL 100

constexpr int NB = 16;       // batch items per block (= MFMA M)
constexpr int WG = 448;      // 7 waves, ALL layer-1; wave 3 also carries layer-2
constexpr int KT = 7;        // K-tiles of 32 ext-slots (224 = 2*112)

#define L2E 1.44269504088896340736f

// R7: interleaved-K fused multiply. A_ext[2i]=bf16hi(h_i), A_ext[2i+1]=
// bf16lo(h_i); B_ext[2i]=bf16hi(w_i), B_ext[2i+1]=bf16mid(w_i). ONE pass of
// K_eff=224 computes (ahi+alo)·(bhi+bmid) = h·w + O(2^-18), 7 MFMA/gate.
// LDS: single plane, granule (16B) = kt*64 + (row ^ (row>>3)), row = reader
// lane for b128 reads (conflict-free). h write-back: k=2u,2u+1 are the two
// halfwords of dword (u&3) in granule (u>>4, m + 16*((u>>2)&3)) -> ONE
// ds_write_b32 per item; residual write pattern is exactly 2-way (counted
// ~2.5e7 by PMC, free per m136 — do not chase).
// R8: wave-parity s_setprio anti-phase. SIMD pairs {0,4},{1,5},{2,6},{3}.
// Waves 4-6 run prio-1 from barrier-exit through their MFMA block: their
// MFMAs drain the matrix pipe first and they enter the trans-heavy update
// phase while waves 0-2's MFMAs then occupy the MFMA pipe -> the serial
// [MFMA 1086 | VALU 1507] per-SIMD phases overlap toward max() instead of
// sum(). Arithmetic byte-identical to R7.
// SCHEDULE NOTE (R4 lesson): keep the update phase BATCHED after all MFMAs —
// hand-interleaving trans ops with dependent MFMAs added ~300us of stall.
#define AG(kt, row) (((kt) * 64 + ((row) ^ ((row) >> 3))) * 4)

typedef short bf16x8 __attribute__((ext_vector_type(8)));
typedef float f32x4 __attribute__((ext_vector_type(4)));

union AF { int4 v; bf16x8 f; unsigned int w[4]; };

__device__ __forceinline__ float frcp(float x) { return __builtin_amdgcn_rcpf(x); }
__device__ __forceinline__ float fexp2(float x) {
#if __has_builtin(__builtin_amdgcn_exp2f)
    return __builtin_amdgcn_exp2f(x);
#else
    return exp2f(x);
#endif
}
// log2e pre-folded into weights/biases (v_exp_f32 IS 2^x).
__device__ __forceinline__ float sig2(float xp) { return frcp(1.0f + fexp2(-xp)); }
__device__ __forceinline__ float th2(float xpp) { return 1.0f - 2.0f * frcp(1.0f + fexp2(xpp)); }
__device__ __forceinline__ float ftanh_n(float x) { return th2(2.0f * L2E * x); }

__device__ __forceinline__ unsigned int cvt_pk_bf16(float lo, float hi) {
    unsigned int d;
    asm("v_cvt_pk_bf16_f32 %0, %1, %2" : "=v"(d) : "v"(lo), "v"(hi));
    return d;
}

// Layer-1: gates padded 100->112 unit-slots; wave w owns all 4 gates of one
// 16-slot group. Slot-group permutation {0,1,2,6,3,4,5} puts the PAD group
// (slots 96..111) on wave 3 (solo on SIMD3). Layer-2 rides in the pad:
// B-column col16==8 of wave 3 holds W_ih2[g] (hi/mid split, same interleave).
// Biases enter as the exact-fp32 MFMA C-input (binit); x rides input-slot
// i=100 (ext-slots 200/201; lane uu==100 deposits x_{t+1} each step; B rows
// 200/201 = W_ih1 hi/mid). Slots i=101..111 stay zero from init.
// Frag layouts (HW-verified): A[m=lane&15][k=32kt+8quad+j];
// B[k][n=lane&15]; D col=lane&15, row=quad*4+reg.
__global__ void __launch_bounds__(WG)
__attribute__((amdgpu_waves_per_eu(2, 2)))
lstm2_kernel(const float* __restrict__ input,   // [B,T]
             const float* __restrict__ W_ih1,   // [400,1]
             const float* __restrict__ W_hh1,   // [400,100]
             const float* __restrict__ b_ih1,   // [400]
             const float* __restrict__ b_hh1,   // [400]
             const float* __restrict__ W_ih2,   // [4,100]
             const float* __restrict__ W_hh2,   // [4,1]
             const float* __restrict__ b_ih2,   // [4]
             const float* __restrict__ b_hh2,   // [4]
             float* __restrict__ out)           // [B,T]
{
    __shared__ __align__(16) unsigned int afrag[2][KT * 256];   // 14 KB interleaved hi/lo

    const int tid = threadIdx.x;
    const int wave = tid >> 6;       // 0..6
    const int lane = tid & 63;
    const int col16 = lane & 15;
    const int quad = lane >> 4;
    const int bg0 = blockIdx.x * NB;
    const bool hiprio = (wave >= 4); // SIMD partner of waves 0..2

    // ---------------- init ----------------
    for (int i = tid; i < 2 * KT * 256; i += WG) (&afrag[0][0])[i] = 0u;

    // slot-group permutation: wave 3 -> group 6 (slots 96..111)
    const int sb = (wave == 3) ? 6 : ((wave < 3) ? wave : wave - 1);
    const int uu = 16 * sb + col16;          // unit-slot owned by this lane
    const bool uvalid = (uu < LL);           // pad slots produce h=0
    const bool l2lane = (wave == 3) && (col16 == 8);   // layer-2 carrier lanes
    const bool xlane = (wave == 3) && (col16 == 4);    // x-depositor lanes (uu==100)
    const bool wr_en = (uu <= 100);          // uu>=101 slots stay 0 forever

    // gate scales folding log2e (i,f,o: sigmoid; g: tanh needs 2x)
    const float gsc[4] = {L2E, L2E, 2.0f * L2E, L2E};

    // Persistent B-fragments, interleaved (hi,mid) along K.
    // Normal lanes: W_hh1 rows (+ W_ih1 at i==100); l2lane: W_ih2 rows.
    bf16x8 bb[4][KT];
#pragma unroll
    for (int g = 0; g < 4; ++g)
#pragma unroll
        for (int kt = 0; kt < KT; ++kt)
#pragma unroll
            for (int j = 0; j < 8; ++j) {
                const int k = 32 * kt + 8 * quad + j;   // ext slot
                const int i = k >> 1;                   // input unit
                float w = 0.0f;
                if (i < LL) {
                    if (l2lane)       w = W_ih2[g * LL + i] * gsc[g];
                    else if (uvalid)  w = W_hh1[(100 * g + uu) * LL + i] * gsc[g];
                } else if (i == 100) {
                    if (!l2lane && uvalid) w = W_ih1[100 * g + uu] * gsc[g];
                }
                const unsigned int hh = cvt_pk_bf16(w, 0.0f) & 0xffffu;
                if (!(k & 1)) {
                    bb[g][kt][j] = (short)hh;
                } else {
                    const float wres = w - __uint_as_float(hh << 16);
                    bb[g][kt][j] = (short)(cvt_pk_bf16(wres, 0.0f) & 0xffffu);
                }
            }

    // Exact fp32 biases as the MFMA C-input.
    f32x4 binit[4];
#pragma unroll
    for (int g = 0; g < 4; ++g) {
        float bv = 0.0f;
        if (l2lane)      bv = (b_ih2[g] + b_hh2[g]) * gsc[g];
        else if (uvalid) bv = (b_ih1[100 * g + uu] + b_hh1[100 * g + uu]) * gsc[g];
        binit[g] = (f32x4){bv, bv, bv, bv};
    }

    float c1[4] = {0.f, 0.f, 0.f, 0.f};

    // write offsets: unit u's (hi,lo) pair = both halfwords of dword (u&3)
    // in granule (sb, m + 16*((col16>>2)&3)); one b32 per item r.
    int wofs[4];
#pragma unroll
    for (int r = 0; r < 4; ++r) {
        const int row = 4 * quad + r + 16 * ((col16 >> 2) & 3);
        wofs[r] = AG(sb, row) + (col16 & 3);
    }

    // Layer-2 recurrent state (l2lane only; 4 items per lane, m = 4*quad+r)
    float wh2s[4], h2v[4] = {0.f, 0.f, 0.f, 0.f}, c2v[4] = {0.f, 0.f, 0.f, 0.f};
#pragma unroll
    for (int g = 0; g < 4; ++g)
        wh2s[g] = l2lane ? W_hh2[g] * gsc[g] : 0.0f;

    __syncthreads();

    // ---- prologue: deposit x_0 (hi|lo packed dword) into phase 0 ----
    if (xlane) {
#pragma unroll
        for (int r = 0; r < 4; ++r) {
            const int m = 4 * quad + r;
            const float x0 = input[(size_t)(bg0 + m) * TT];
            const unsigned int hh = cvt_pk_bf16(x0, x0);
            const float hf = __uint_as_float(hh << 16);
            afrag[0][wofs[r]] = cvt_pk_bf16(x0, x0 - hf);
        }
    }
    __syncthreads();

    // ---------------- time loop (one barrier per step) ----------------
    for (int t = 0; t <= TT; ++t) {
        const int p = t & 1, pn = p ^ 1;

        // wave 3 also runs at t==TT to produce the final layer-2 output
        if (t < TT || wave == 3) {
            // R8: hi waves rush loads+MFMA at prio 1, then drop to 0 for the
            // trans phase -> anti-phase with their SIMD partner wave.
            if (hiprio) __builtin_amdgcn_s_setprio(1);

            // x_{t+1} prefetch (4 lanes of wave 3; L2-resident lines).
            float xnext[4] = {0.f, 0.f, 0.f, 0.f};
            if (xlane && t + 1 < TT) {
#pragma unroll
                for (int r = 0; r < 4; ++r)
                    xnext[r] = input[(size_t)(bg0 + 4 * quad + r) * TT + (t + 1)];
            }

            // ---- A-frags (interleaved hi/lo of h1_{t-1}): b128 -> MFMA ----
            AF a[KT];
#pragma unroll
            for (int kt = 0; kt < KT; ++kt)
                a[kt].v = *(const int4*)&afrag[p][AG(kt, lane)];

            // single fused pass: 7 kt x 4 gates, bias preloaded via C
            f32x4 acc[4];
#pragma unroll
            for (int g = 0; g < 4; ++g)
                acc[g] = __builtin_amdgcn_mfma_f32_16x16x32_bf16(a[0].f, bb[g][0], binit[g], 0, 0, 0);
#pragma unroll
            for (int kt = 1; kt < KT; ++kt)
#pragma unroll
                for (int g = 0; g < 4; ++g)
                    acc[g] = __builtin_amdgcn_mfma_f32_16x16x32_bf16(a[kt].f, bb[g][kt], acc[g], 0, 0, 0);

            if (hiprio) __builtin_amdgcn_s_setprio(0);

            // ---- layer 2 (l2lane): acc[g][r] = b2 + dot(W_ih2[g], h1_{t-1}[4q+r]) ----
            if (l2lane && t >= 1) {
#pragma unroll
                for (int r = 0; r < 4; ++r) {
                    const float p0 = fmaf(wh2s[0], h2v[r], acc[0][r]);
                    const float p1 = fmaf(wh2s[1], h2v[r], acc[1][r]);
                    const float p2 = fmaf(wh2s[2], h2v[r], acc[2][r]);
                    const float p3 = fmaf(wh2s[3], h2v[r], acc[3][r]);
                    const float i2 = sig2(p0), f2 = sig2(p1), g2 = th2(p2), o2 = sig2(p3);
                    c2v[r] = f2 * c2v[r] + i2 * g2;
                    h2v[r] = o2 * ftanh_n(c2v[r]);
                    out[(size_t)(bg0 + 4 * quad + r) * TT + (t - 1)] = h2v[r];
                }
            }

            // ---- layer-1 cell update + single-dword (hi|lo) write-back ----
            if (t < TT) {
#pragma unroll
                for (int r = 0; r < 4; ++r) {
                    // bias and x already inside acc -> gates are acc directly
                    const float iv = sig2(acc[0][r]);
                    const float fv = sig2(acc[1][r]);
                    const float gv = th2(acc[2][r]);
                    const float ov = sig2(acc[3][r]);
                    const float c = fv * c1[r] + iv * gv;
                    c1[r] = c;
                    // valid units: h; lane uu==100 carries x_{t+1}
                    const float h = uvalid ? (ov * ftanh_n(c)) : xnext[r];
                    if (wr_en) {
                        const unsigned int hh = cvt_pk_bf16(h, h);   // low16 = bf16rn(h)
                        const float hf = __uint_as_float(hh << 16);
                        afrag[pn][wofs[r]] = cvt_pk_bf16(h, h - hf); // hi | lo<<16
                    }
                }
            }
        }

        __syncthreads();   // h1_t (afrag[pn]) visible for step t+1
    }
}

extern "C" void kernel_launch(void* const* d_in, const int* in_sizes, int n_in,
                              void* d_out, int out_size, void* d_ws, size_t ws_size,
                              hipStream_t stream) {
    const float* input = (const float*)d_in[0];
    const float* W_ih1 = (const float*)d_in[1];
    const float* W_hh1 = (const float*)d_in[2];
    const float* b_ih1 = (const float*)d_in[3];
    const float* b_hh1 = (const float*)d_in[4];
    const float* W_ih2 = (const float*)d_in[5];
    const float* W_hh2 = (const float*)d_in[6];
    const float* b_ih2 = (const float*)d_in[7];
    const float* b_hh2 = (const float*)d_in[8];
    float* out = (float*)d_out;

    dim3 grid(BB / NB);   // 256 workgroups -> 1 per CU
    dim3 block(WG);       // 448 threads = 7 waves
    lstm2_kernel<<<grid, block, 0, stream>>>(input, W_ih1, W_hh1, b_ih1, b_hh1,
                                             W_ih2, W_hh2, b_ih2, b_hh2, out);
}